// Round 6
// baseline (570.401 us; speedup 1.0000x reference)
//
#include <hip/hip_runtime.h>
#include <hip/hip_cooperative_groups.h>

namespace cg = cooperative_groups;

#define N_NODES 50000
#define N_EDGES 800000
#define WT_PAD 136      // LDS row stride in shorts (272 B: 16B-aligned, 2-way-free banks)
#define DUMMY N_NODES   // g row 50000 is zeroed; CSR padding points here
#define SLOT_LOG 6      // 64 slots per node (max degree ~45 for Poisson(16))
#define AGG_HALF_BLKS 1563  // ceil(50000/32) virtual blocks per channel-half

#define NBUCK 391       // ceil(50000/128) buckets of 128 nodes
#define BUCK_CAP 3072   // mean 2046, sigma ~45 -> +22 sigma headroom
#define EPB 4096        // edges per partition virtual block
#define PART_BLOCKS 196 // ceil(800000/4096)
#define GEMM_BLOCKS 782 // ceil(50000/64)
#define PREP_BLOCKS 66
#define SMEM_BYTES 34816  // max(partition 24576, gemm 34816, csr 16896)

typedef __attribute__((ext_vector_type(8))) short short8;   // 8 bf16 = one MFMA A/B frag
typedef __attribute__((ext_vector_type(4))) float floatx4;  // MFMA C/D frag / NT stores

__device__ __forceinline__ short f2bf(float f) {  // RNE float->bf16
    union { float f; unsigned u; } v; v.f = f;
    unsigned r = v.u + 0x7fff + ((v.u >> 16) & 1);
    return (short)(r >> 16);
}
__device__ __forceinline__ float bflo(unsigned u) {
    union { unsigned u; float f; } v; v.u = u << 16; return v.f;
}
__device__ __forceinline__ float bfhi(unsigned u) {
    union { unsigned u; float f; } v; v.u = u & 0xffff0000u; return v.f;
}

// ---------------- phase 0: weights transpose/fuse + zero bucket counters --------------

__device__ __forceinline__ void phase_prep(const float* __restrict__ W1,
                                           const float* __restrict__ W2,
                                           const float* __restrict__ W3,
                                           const float* __restrict__ b2,
                                           const float* __restrict__ b3,
                                           unsigned short* __restrict__ Wt1,
                                           unsigned short* __restrict__ Wt23,
                                           float* __restrict__ b23,
                                           int* __restrict__ bucket_cnt,
                                           unsigned int* __restrict__ gdummy, int vb) {
    int i = vb * 256 + threadIdx.x;
    if (i < 128 * 128) {
        int n = i >> 7, k = i & 127;
        Wt1[i] = (unsigned short)f2bf(W1[k * 128 + n]);
        float w = (n < 64) ? W2[k * 64 + n] : W3[k * 64 + (n - 64)];
        Wt23[i] = (unsigned short)f2bf(w);
    } else if (i < 128 * 128 + 128) {
        int k2 = i - 128 * 128;
        b23[k2] = (k2 < 64) ? b2[k2] : b3[k2 - 64];
    } else if (i < 128 * 128 + 192) {
        gdummy[i - (128 * 128 + 128)] = 0;           // 64 uints = 128 bf16 zeros
    }
    if (i < NBUCK) bucket_cnt[i] = 0;
}

// ---------------- phase A: radix-partition edges into 391 dst-buckets -----------------
// LDS histogram -> scan -> one global atomic per (vblock,bucket) -> bucket-sorted LDS
// staging -> coalesced flush (dest index recomputed from s_shift: no dsti array).

__device__ __forceinline__ void phase_partition(char* smem, const int* __restrict__ ei,
                                                int* __restrict__ bucket_cnt,
                                                unsigned* __restrict__ bucket_data, int vb) {
    int* hcnt    = (int*)smem;               // 512
    int* hscan   = hcnt + 512;
    int* htmp    = hscan + 512;
    int* s_shift = htmp + 512;               // ends at byte 8192
    unsigned* stg = (unsigned*)(s_shift + 512);  // EPB entries -> byte 24576
    int tid = threadIdx.x;
    int e0 = vb * EPB;

    for (int i = tid; i < 512; i += 256) hcnt[i] = 0;
    __syncthreads();
    for (int j = tid; j < EPB; j += 256) {
        int e = e0 + j;
        if (e < N_EDGES) atomicAdd(&hcnt[ei[N_EDGES + e] >> 7], 1);
    }
    __syncthreads();
    for (int i = tid; i < 512; i += 256) hscan[i] = hcnt[i];
    __syncthreads();
    for (int off = 1; off < 512; off <<= 1) {           // Hillis-Steele inclusive scan
        for (int i = tid; i < 512; i += 256) htmp[i] = hscan[i] + (i >= off ? hscan[i - off] : 0);
        __syncthreads();
        for (int i = tid; i < 512; i += 256) hscan[i] = htmp[i];
        __syncthreads();
    }
    for (int b = tid; b < NBUCK; b += 256) {
        int c = hcnt[b];
        int excl = hscan[b] - c;
        int gg = (c > 0) ? atomicAdd(&bucket_cnt[b], c) : 0;
        s_shift[b] = gg - excl;                         // global base minus local base
        htmp[b] = excl;                                 // htmp reused as cursor
    }
    __syncthreads();
    for (int j = tid; j < EPB; j += 256) {              // stage bucket-sorted
        int e = e0 + j;
        if (e < N_EDGES) {
            int src = ei[e];
            int d = ei[N_EDGES + e];
            int pos = atomicAdd(&htmp[d >> 7], 1);      // LDS cursor
            stg[pos] = ((unsigned)d << 16) | (unsigned)src;   // both ids < 2^16
        }
    }
    __syncthreads();
    int tot = N_EDGES - e0; if (tot > EPB) tot = EPB;
    for (int j = tid; j < tot; j += 256) {              // coalesced runs per bucket
        unsigned wv = stg[j];
        int b = (int)(wv >> 23);                        // dst>>7
        int gidx = s_shift[b] + j;                      // offset within bucket region
        if (gidx < BUCK_CAP) bucket_data[b * BUCK_CAP + gidx] = wv;
    }
    __syncthreads();
}

// ---------------- phase B: per-bucket CSR rows built entirely in LDS ------------------

__device__ __forceinline__ void phase_csr(char* smem, const unsigned* __restrict__ bucket_data,
                                          const int* __restrict__ bucket_cnt,
                                          int* __restrict__ counts,
                                          unsigned short* __restrict__ sorted_src, int b) {
    uint4* slots4 = (uint4*)smem;                       // 128 rows x 64 shorts = 16 KB
    int* ctr = (int*)(smem + 16384);
    unsigned short* slots = (unsigned short*)slots4;
    int tid = threadIdx.x;

    for (int i = tid; i < 128; i += 256) ctr[i] = 0;
    const unsigned dpat = ((unsigned)DUMMY) | (((unsigned)DUMMY) << 16);
    for (int i = tid; i < 1024; i += 256) slots4[i] = make_uint4(dpat, dpat, dpat, dpat);
    __syncthreads();

    int cnt = bucket_cnt[b]; if (cnt > BUCK_CAP) cnt = BUCK_CAP;
    const unsigned* bd = bucket_data + b * BUCK_CAP;
    for (int j = tid; j < cnt; j += 256) {
        unsigned w2 = bd[j];
        int dl = (int)((w2 >> 16) & 127);
        int r = atomicAdd(&ctr[dl], 1);                 // LDS atomic: fast
        if (r < 64) slots[(dl << 6) + r] = (unsigned short)(w2 & 0xffffu);
    }
    __syncthreads();

    int node0 = b << 7;
    for (int i = tid; i < 128; i += 256)
        if (node0 + i < N_NODES) counts[node0 + i] = ctr[i];
    uint4* gs = (uint4*)(sorted_src + ((size_t)node0 << SLOT_LOG));
    for (int k = tid; k < 1024; k += 256) {             // 8 uint4 per row, coalesced
        int row = k >> 3;
        if (node0 + row < N_NODES) gs[k] = slots4[k];
    }
    __syncthreads();
}

// ---------------- phase C/E: MFMA GEMM g[n] = bf16(dinv[n] * (A@W)[n]) ----------------

template <bool A_BF16>
__device__ __forceinline__ void phase_gemm(char* smem, const void* __restrict__ Ain,
                                           const unsigned short* __restrict__ Wt,
                                           const int* __restrict__ degs,
                                           unsigned short* __restrict__ g, int vb) {
    unsigned short* lds = (unsigned short*)smem;        // 128 * WT_PAD shorts = 34816 B
    int tid = threadIdx.x;
    int wave = tid >> 6, lane = tid & 63;
    int quad = lane >> 4, ln = lane & 15;

    {   // stage Wt (16384 shorts)
        int r = tid >> 1, h = tid & 1;
        const int4* src = (const int4*)(Wt + r * 128 + h * 64);
#pragma unroll
        for (int i = 0; i < 8; ++i)
            *(int4*)&lds[r * WT_PAD + h * 64 + i * 8] = src[i];
    }

    int row_base = vb * 64 + wave * 16;
    int arow = row_base + ln;
    bool ok = arow < N_NODES;
    short8 afrag[4];
    if (A_BF16) {
        const unsigned short* A = (const unsigned short*)Ain;
#pragma unroll
        for (int kk = 0; kk < 4; ++kk) {
            short8 v = {};
            if (ok) v = *(const short8*)(A + arow * 128 + kk * 32 + quad * 8);
            afrag[kk] = v;
        }
    } else {
        const float* A = (const float*)Ain;
#pragma unroll
        for (int kk = 0; kk < 4; ++kk) {
            short8 v = {};
            if (ok) {
                const floatx4* p = (const floatx4*)(A + arow * 128 + kk * 32 + quad * 8);
                floatx4 fa = p[0], fb = p[1];
                v[0] = f2bf(fa.x); v[1] = f2bf(fa.y); v[2] = f2bf(fa.z); v[3] = f2bf(fa.w);
                v[4] = f2bf(fb.x); v[5] = f2bf(fb.y); v[6] = f2bf(fb.z); v[7] = f2bf(fb.w);
            }
            afrag[kk] = v;
        }
    }
    __syncthreads();

    floatx4 acc[8] = {};
#pragma unroll
    for (int n0 = 0; n0 < 8; ++n0) {
#pragma unroll
        for (int kk = 0; kk < 4; ++kk) {
            short8 b = *(const short8*)&lds[(n0 * 16 + ln) * WT_PAD + kk * 32 + quad * 8];
            acc[n0] = __builtin_amdgcn_mfma_f32_16x16x32_bf16(afrag[kk], b, acc[n0], 0, 0, 0);
        }
    }

    __syncthreads();  // done with Wt; reuse LDS for epilogue transpose
    unsigned short* st = &lds[wave * 16 * WT_PAD];
    float dv[4];
#pragma unroll
    for (int r = 0; r < 4; ++r) {
        int node = row_base + quad * 4 + r;
        dv[r] = (node < N_NODES) ? rsqrtf((float)(degs[node] + 1)) : 0.f;
    }
#pragma unroll
    for (int n0 = 0; n0 < 8; ++n0)
#pragma unroll
        for (int r = 0; r < 4; ++r)
            st[(quad * 4 + r) * WT_PAD + n0 * 16 + ln] =
                (unsigned short)f2bf(acc[n0][r] * dv[r]);
    __syncthreads();

#pragma unroll
    for (int i = 0; i < 4; ++i) {
        int row = i * 4 + quad;
        int node = row_base + row;
        short8 v = *(const short8*)&st[row * WT_PAD + ln * 8];
        if (node < N_NODES) *(short8*)(g + node * 128 + ln * 8) = v;
    }
    __syncthreads();  // protect LDS across virtual-block iterations
}

// ---------------- phase D/F: aggregation (round-3 form: 8 lanes/node, split halves) ----

template <int MODE>  // 0: bf16 out [N][128]; 1: fp32 split out (x1 | x2 by half)
__device__ __forceinline__ void phase_agg(const unsigned short* __restrict__ g,
                                          const int* __restrict__ degs,
                                          const unsigned short* __restrict__ srcs,
                                          const float* __restrict__ bias,
                                          void* __restrict__ outp, int vb) {
    int h = 0, nb = vb;
    if (nb >= AGG_HALF_BLKS) { h = 1; nb -= AGG_HALF_BLKS; }
    int n = nb * 32 + (threadIdx.x >> 3);
    if (n >= N_NODES) return;                   // device fn: safe, no barriers inside
    int c4 = threadIdx.x & 7;                   // uint4 index within the half-row
    int hoff = h * 8;
    const uint4* grow = (const uint4*)g;        // 16 uint4 per full row
    uint4 u = grow[n * 16 + hoff + c4];         // self-loop term
    float a0 = bflo(u.x), a1 = bfhi(u.x), a2 = bflo(u.y), a3 = bfhi(u.y);
    float a4 = bflo(u.z), a5 = bfhi(u.z), a6 = bflo(u.w), a7 = bfhi(u.w);
    float c0 = 0.f, c1 = 0.f, c2 = 0.f, c3 = 0.f, c5 = 0.f, c6 = 0.f, c7 = 0.f, c8 = 0.f;
    int deg = degs[n];
    int degc = deg > 64 ? 64 : deg;
    int beg = n << SLOT_LOG;
    int pend = beg + ((degc + 3) & ~3);         // pad slots hold DUMMY (zero row)
    int e = beg;
    for (; e + 8 <= pend; e += 8) {
        ushort4 sa = *(const ushort4*)&srcs[e];
        ushort4 sb = *(const ushort4*)&srcs[e + 4];
        uint4 v0 = grow[sa.x * 16 + hoff + c4];
        uint4 v1 = grow[sa.y * 16 + hoff + c4];
        uint4 v2 = grow[sa.z * 16 + hoff + c4];
        uint4 v3 = grow[sa.w * 16 + hoff + c4];
        uint4 v4 = grow[sb.x * 16 + hoff + c4];
        uint4 v5 = grow[sb.y * 16 + hoff + c4];
        uint4 v6 = grow[sb.z * 16 + hoff + c4];
        uint4 v7 = grow[sb.w * 16 + hoff + c4];
        a0 += bflo(v0.x); a1 += bfhi(v0.x); a2 += bflo(v0.y); a3 += bfhi(v0.y);
        a4 += bflo(v0.z); a5 += bfhi(v0.z); a6 += bflo(v0.w); a7 += bfhi(v0.w);
        c0 += bflo(v1.x); c1 += bfhi(v1.x); c2 += bflo(v1.y); c3 += bfhi(v1.y);
        c5 += bflo(v1.z); c6 += bfhi(v1.z); c7 += bflo(v1.w); c8 += bfhi(v1.w);
        a0 += bflo(v2.x); a1 += bfhi(v2.x); a2 += bflo(v2.y); a3 += bfhi(v2.y);
        a4 += bflo(v2.z); a5 += bfhi(v2.z); a6 += bflo(v2.w); a7 += bfhi(v2.w);
        c0 += bflo(v3.x); c1 += bfhi(v3.x); c2 += bflo(v3.y); c3 += bfhi(v3.y);
        c5 += bflo(v3.z); c6 += bfhi(v3.z); c7 += bflo(v3.w); c8 += bfhi(v3.w);
        a0 += bflo(v4.x); a1 += bfhi(v4.x); a2 += bflo(v4.y); a3 += bfhi(v4.y);
        a4 += bflo(v4.z); a5 += bfhi(v4.z); a6 += bflo(v4.w); a7 += bfhi(v4.w);
        c0 += bflo(v5.x); c1 += bfhi(v5.x); c2 += bflo(v5.y); c3 += bfhi(v5.y);
        c5 += bflo(v5.z); c6 += bfhi(v5.z); c7 += bflo(v5.w); c8 += bfhi(v5.w);
        a0 += bflo(v6.x); a1 += bfhi(v6.x); a2 += bflo(v6.y); a3 += bfhi(v6.y);
        a4 += bflo(v6.z); a5 += bfhi(v6.z); a6 += bflo(v6.w); a7 += bfhi(v6.w);
        c0 += bflo(v7.x); c1 += bfhi(v7.x); c2 += bflo(v7.y); c3 += bfhi(v7.y);
        c5 += bflo(v7.z); c6 += bfhi(v7.z); c7 += bflo(v7.w); c8 += bfhi(v7.w);
    }
    if (e < pend) {  // exactly one 4-wide chunk (pend-beg is a multiple of 4)
        ushort4 sa = *(const ushort4*)&srcs[e];
        uint4 v0 = grow[sa.x * 16 + hoff + c4];
        uint4 v1 = grow[sa.y * 16 + hoff + c4];
        uint4 v2 = grow[sa.z * 16 + hoff + c4];
        uint4 v3 = grow[sa.w * 16 + hoff + c4];
        a0 += bflo(v0.x); a1 += bfhi(v0.x); a2 += bflo(v0.y); a3 += bfhi(v0.y);
        a4 += bflo(v0.z); a5 += bfhi(v0.z); a6 += bflo(v0.w); a7 += bfhi(v0.w);
        c0 += bflo(v1.x); c1 += bfhi(v1.x); c2 += bflo(v1.y); c3 += bfhi(v1.y);
        c5 += bflo(v1.z); c6 += bfhi(v1.z); c7 += bflo(v1.w); c8 += bfhi(v1.w);
        a0 += bflo(v2.x); a1 += bfhi(v2.x); a2 += bflo(v2.y); a3 += bfhi(v2.y);
        a4 += bflo(v2.z); a5 += bfhi(v2.z); a6 += bflo(v2.w); a7 += bfhi(v2.w);
        c0 += bflo(v3.x); c1 += bfhi(v3.x); c2 += bflo(v3.y); c3 += bfhi(v3.y);
        c5 += bflo(v3.z); c6 += bfhi(v3.z); c7 += bflo(v3.w); c8 += bfhi(v3.w);
    }
    a0 += c0; a1 += c1; a2 += c2; a3 += c3; a4 += c5; a5 += c6; a6 += c7; a7 += c8;
    float d = rsqrtf((float)(deg + 1));
    float4 bv0 = ((const float4*)bias)[h * 16 + c4 * 2];
    float4 bv1 = ((const float4*)bias)[h * 16 + c4 * 2 + 1];
    float o0 = fmaxf(d * a0 + bv0.x, 0.f);
    float o1 = fmaxf(d * a1 + bv0.y, 0.f);
    float o2 = fmaxf(d * a2 + bv0.z, 0.f);
    float o3 = fmaxf(d * a3 + bv0.w, 0.f);
    float o4 = fmaxf(d * a4 + bv1.x, 0.f);
    float o5 = fmaxf(d * a5 + bv1.y, 0.f);
    float o6 = fmaxf(d * a6 + bv1.z, 0.f);
    float o7 = fmaxf(d * a7 + bv1.w, 0.f);
    if (MODE == 0) {
        uint4 w;
        w.x = ((unsigned)(unsigned short)f2bf(o0)) | (((unsigned)(unsigned short)f2bf(o1)) << 16);
        w.y = ((unsigned)(unsigned short)f2bf(o2)) | (((unsigned)(unsigned short)f2bf(o3)) << 16);
        w.z = ((unsigned)(unsigned short)f2bf(o4)) | (((unsigned)(unsigned short)f2bf(o5)) << 16);
        w.w = ((unsigned)(unsigned short)f2bf(o6)) | (((unsigned)(unsigned short)f2bf(o7)) << 16);
        ((uint4*)outp)[n * 16 + hoff + c4] = w;   // hidden is reused by gemm2: keep cached
    } else {
        // half 0 == x1 exactly; half 1 == x2 exactly (64 ch each, fp32)
        float* out = (float*)outp + (size_t)h * N_NODES * 64;
        floatx4* o = (floatx4*)out + n * 16 + c4 * 2;
        floatx4 w0; w0.x = o0; w0.y = o1; w0.z = o2; w0.w = o3;
        floatx4 w1; w1.x = o4; w1.y = o5; w1.z = o6; w1.w = o7;
        __builtin_nontemporal_store(w0, o);
        __builtin_nontemporal_store(w1, o + 1);
    }
}

// ---------------- the cooperative mega-kernel (7 phases, 6 grid syncs) ----------------

__global__ __launch_bounds__(256, 4) void mega(const float* __restrict__ x,
                                               const int* __restrict__ ei,
                                               const float* __restrict__ W1,
                                               const float* __restrict__ b1,
                                               const float* __restrict__ W2,
                                               const float* __restrict__ b2,
                                               const float* __restrict__ W3,
                                               const float* __restrict__ b3,
                                               float* __restrict__ out,
                                               int* counts, int* bucket_cnt,
                                               unsigned short* Wt1, unsigned short* Wt23,
                                               float* b23, unsigned* bucket_data,
                                               unsigned short* sorted_src,
                                               unsigned short* g1, unsigned short* hidden) {
    __shared__ __align__(16) char smem[SMEM_BYTES];
    cg::grid_group grid = cg::this_grid();
    int bid = blockIdx.x, gsz = gridDim.x;

    for (int vb = bid; vb < PREP_BLOCKS; vb += gsz)
        phase_prep(W1, W2, W3, b2, b3, Wt1, Wt23, b23, bucket_cnt,
                   (unsigned int*)(g1 + N_NODES * 128), vb);
    grid.sync();
    for (int vb = bid; vb < PART_BLOCKS; vb += gsz)
        phase_partition(smem, ei, bucket_cnt, bucket_data, vb);
    grid.sync();
    for (int vb = bid; vb < NBUCK; vb += gsz)
        phase_csr(smem, bucket_data, bucket_cnt, counts, sorted_src, vb);
    grid.sync();
    for (int vb = bid; vb < GEMM_BLOCKS; vb += gsz)
        phase_gemm<false>(smem, x, Wt1, counts, g1, vb);
    grid.sync();
    for (int vb = bid; vb < 2 * AGG_HALF_BLKS; vb += gsz)
        phase_agg<0>(g1, counts, sorted_src, b1, hidden, vb);
    grid.sync();
    for (int vb = bid; vb < GEMM_BLOCKS; vb += gsz)
        phase_gemm<true>(smem, hidden, Wt23, counts, g1, vb);
    grid.sync();
    for (int vb = bid; vb < 2 * AGG_HALF_BLKS; vb += gsz)
        phase_agg<1>(g1, counts, sorted_src, b23, out, vb);
}

// ---------------- launch ----------------

extern "C" void kernel_launch(void* const* d_in, const int* in_sizes, int n_in,
                              void* d_out, int out_size, void* d_ws, size_t ws_size,
                              hipStream_t stream) {
    const float* x  = (const float*)d_in[0];
    const int*   ei = (const int*)d_in[1];   // [2, E] int32
    const float* W1 = (const float*)d_in[2];
    const float* b1 = (const float*)d_in[3];
    const float* W2 = (const float*)d_in[4];
    const float* b2 = (const float*)d_in[5];
    const float* W3 = (const float*)d_in[6];
    const float* b3 = (const float*)d_in[7];
    float* out = (float*)d_out;

    // Workspace layout (non-overlapping; total 37,083,392 B, previously proven)
    char* w = (char*)d_ws;
    int*            counts      = (int*)(w + 0);                   // 200,000 B (true degree)
    int*            bucket_cnt  = (int*)(w + 200704);              // 1,564 B
    unsigned short* Wt1         = (unsigned short*)(w + 204800);   // 32,768 B
    unsigned short* Wt23        = (unsigned short*)(w + 237568);   // 32,768 B
    float*          b23         = (float*)(w + 270336);            // 512 B
    unsigned*       bucket_data = (unsigned*)(w + 278528);         // 4,804,608 B
    unsigned short* sorted_src  = (unsigned short*)(w + 5083136);  // 6,400,000 B
    unsigned short* g1          = (unsigned short*)(w + 11483136); // 12,800,256 B (+dummy row)
    unsigned short* hidden      = (unsigned short*)(w + 24283392); // 12,800,000 B

    // Co-resident grid size: occupancy API x CU count (deadlock-safe), computed once.
    static int coop_grid = 0;
    if (coop_grid == 0) {
        int nb = 0;
        hipError_t e1 = hipOccupancyMaxActiveBlocksPerMultiprocessor(
            &nb, reinterpret_cast<const void*>(mega), 256, 0);
        int dev = 0, ncu = 0;
        hipGetDevice(&dev);
        hipError_t e2 = hipDeviceGetAttribute(&ncu, hipDeviceAttributeMultiprocessorCount, dev);
        coop_grid = (e1 == hipSuccess && e2 == hipSuccess && nb > 0 && ncu > 0) ? nb * ncu : 512;
        if (coop_grid > 2 * AGG_HALF_BLKS) coop_grid = 2 * AGG_HALF_BLKS;
    }

    void* args[] = {(void*)&x, (void*)&ei, (void*)&W1, (void*)&b1, (void*)&W2, (void*)&b2,
                    (void*)&W3, (void*)&b3, (void*)&out, (void*)&counts, (void*)&bucket_cnt,
                    (void*)&Wt1, (void*)&Wt23, (void*)&b23, (void*)&bucket_data,
                    (void*)&sorted_src, (void*)&g1, (void*)&hidden};
    hipLaunchCooperativeKernel(reinterpret_cast<const void*>(mega), dim3(coop_grid),
                               dim3(256), args, 0, stream);
}

// Round 7
// 191.426 us; speedup vs baseline: 2.9797x; 2.9797x over previous
//
#include <hip/hip_runtime.h>

#define N_NODES 50000
#define N_EDGES 800000
#define CH 128
#define WT_PAD 136      // LDS row stride in shorts (272 B: 16B-aligned, 2-way-free banks)
#define DUMMY N_NODES   // g row 50000 is zeroed; CSR padding points here
#define SLOT_LOG 6      // 64 slots per node (max degree ~45 for Poisson(16))
#define AGG_HALF_BLKS 1563  // ceil(50000/32) blocks per channel-half

#define NBUCK 782       // ceil(50000/64) buckets of 64 nodes (load-balanced csr_build)
#define HIST 1024       // padded histogram size (pow2 >= NBUCK)
#define BUCK_CAP 1536   // mean 1023, sigma ~32 -> +16 sigma headroom
#define EPB 4096        // edges per partition block
#define PART_BLOCKS 196 // ceil(800000/4096): one balanced wave over 256 CUs

typedef __attribute__((ext_vector_type(8))) short short8;   // 8 bf16 = one MFMA A/B frag
typedef __attribute__((ext_vector_type(4))) float floatx4;  // MFMA C/D frag / NT stores

__device__ __forceinline__ short f2bf(float f) {  // RNE float->bf16
    union { float f; unsigned u; } v; v.f = f;
    unsigned r = v.u + 0x7fff + ((v.u >> 16) & 1);
    return (short)(r >> 16);
}
__device__ __forceinline__ float bflo(unsigned u) {
    union { unsigned u; float f; } v; v.u = u << 16; return v.f;
}
__device__ __forceinline__ float bfhi(unsigned u) {
    union { unsigned u; float f; } v; v.u = u & 0xffff0000u; return v.f;
}

// ---------------- prep: weights transpose/fuse + zero bucket counters -----------------

__global__ __launch_bounds__(256) void prep_kernel(const float* __restrict__ W1,
                                                   const float* __restrict__ W2,
                                                   const float* __restrict__ W3,
                                                   const float* __restrict__ b2,
                                                   const float* __restrict__ b3,
                                                   unsigned short* __restrict__ Wt1,
                                                   unsigned short* __restrict__ Wt23,
                                                   float* __restrict__ b23,
                                                   int* __restrict__ bucket_cnt,
                                                   unsigned int* __restrict__ gdummy) {
    int i = blockIdx.x * blockDim.x + threadIdx.x;   // 66*256 = 16896 threads
    if (i < 128 * 128) {
        int n = i >> 7, k = i & 127;
        Wt1[i] = (unsigned short)f2bf(W1[k * 128 + n]);
        float w = (n < 64) ? W2[k * 64 + n] : W3[k * 64 + (n - 64)];
        Wt23[i] = (unsigned short)f2bf(w);
    } else if (i < 128 * 128 + 128) {
        int k2 = i - 128 * 128;
        b23[k2] = (k2 < 64) ? b2[k2] : b3[k2 - 64];
    } else if (i < 128 * 128 + 192) {
        gdummy[i - (128 * 128 + 128)] = 0;           // 64 uints = 128 bf16 zeros
    }
    if (i < NBUCK) bucket_cnt[i] = 0;
}

// ---------------- Phase A: radix-partition edges into 782 dst-buckets -----------------
// Per block: LDS histogram -> LDS scan -> one global atomic per (block,bucket) ->
// bucket-sorted LDS staging -> coalesced flush (dest recomputed from s_shift; no dsti).

__global__ __launch_bounds__(256) void partition(const int* __restrict__ ei,
                                                 int* __restrict__ bucket_cnt,
                                                 unsigned* __restrict__ bucket_data) {
    __shared__ int hcnt[HIST], hscan[HIST], htmp[HIST];  // hist + inclusive scan (ping-pong)
    __shared__ int s_shift[HIST];                        // global base - local base
    __shared__ unsigned stg[EPB];                        // bucket-sorted packed edges
    int tid = threadIdx.x;
    int e0 = blockIdx.x * EPB;

    for (int i = tid; i < HIST; i += 256) hcnt[i] = 0;
    __syncthreads();
    for (int j = tid; j < EPB; j += 256) {
        int e = e0 + j;
        if (e < N_EDGES) atomicAdd(&hcnt[ei[N_EDGES + e] >> 6], 1);
    }
    __syncthreads();
    for (int i = tid; i < HIST; i += 256) hscan[i] = hcnt[i];
    __syncthreads();
    for (int off = 1; off < HIST; off <<= 1) {          // Hillis-Steele inclusive scan
        for (int i = tid; i < HIST; i += 256) htmp[i] = hscan[i] + (i >= off ? hscan[i - off] : 0);
        __syncthreads();
        for (int i = tid; i < HIST; i += 256) hscan[i] = htmp[i];
        __syncthreads();
    }
    // exclusive base_l = hscan - hcnt; allocate global space; cursor starts at base_l
    for (int b = tid; b < NBUCK; b += 256) {
        int c = hcnt[b];
        int excl = hscan[b] - c;
        int g = (c > 0) ? atomicAdd(&bucket_cnt[b], c) : 0;
        s_shift[b] = g - excl;
        htmp[b] = excl;                                 // htmp reused as cursor
    }
    __syncthreads();
    for (int j = tid; j < EPB; j += 256) {              // stage bucket-sorted
        int e = e0 + j;
        if (e < N_EDGES) {
            int src = ei[e];
            int d = ei[N_EDGES + e];
            int pos = atomicAdd(&htmp[d >> 6], 1);      // LDS cursor
            stg[pos] = ((unsigned)d << 16) | (unsigned)src;   // both ids < 2^16
        }
    }
    __syncthreads();
    int tot = N_EDGES - e0; if (tot > EPB) tot = EPB;
    for (int j = tid; j < tot; j += 256) {              // coalesced runs per bucket
        unsigned wv = stg[j];
        int b = (int)(wv >> 22);                        // dst >> 6
        int gidx = s_shift[b] + j;                      // offset within bucket region
        if (gidx < BUCK_CAP) bucket_data[b * BUCK_CAP + gidx] = wv;
    }
}

// ---------------- Phase B: per-bucket CSR rows built entirely in LDS ------------------
// 64 nodes/bucket -> 782 blocks (balanced over 256 CUs), 8 KB slot tile per block.

__global__ __launch_bounds__(256) void csr_build(const unsigned* __restrict__ bucket_data,
                                                 const int* __restrict__ bucket_cnt,
                                                 int* __restrict__ counts,
                                                 unsigned short* __restrict__ sorted_src) {
    __shared__ uint4 slots4[512];                       // 64 rows x 64 shorts = 8 KB
    __shared__ int ctr[64];
    unsigned short* slots = (unsigned short*)slots4;
    int tid = threadIdx.x, b = blockIdx.x;

    if (tid < 64) ctr[tid] = 0;
    const unsigned dpat = ((unsigned)DUMMY) | (((unsigned)DUMMY) << 16);
    for (int i = tid; i < 512; i += 256) slots4[i] = make_uint4(dpat, dpat, dpat, dpat);
    __syncthreads();

    int cnt = bucket_cnt[b]; if (cnt > BUCK_CAP) cnt = BUCK_CAP;
    const unsigned* bd = bucket_data + b * BUCK_CAP;
    for (int j = tid; j < cnt; j += 256) {
        unsigned w = bd[j];
        int dl = (int)((w >> 16) & 63);
        int r = atomicAdd(&ctr[dl], 1);                 // LDS atomic: fast
        if (r < 64) slots[(dl << 6) + r] = (unsigned short)(w & 0xffffu);
    }
    __syncthreads();

    int node0 = b << 6;
    if (tid < 64 && node0 + tid < N_NODES) counts[node0 + tid] = ctr[tid];
    uint4* gs = (uint4*)(sorted_src + ((size_t)node0 << SLOT_LOG));
    for (int k = tid; k < 512; k += 256) {              // 8 uint4 per row, coalesced
        int row = k >> 3;
        if (node0 + row < N_NODES) gs[k] = slots4[k];
    }
}

// ---------------- MFMA GEMM: g[n][ch] = bf16( dinv[n] * sum_c A[n][c]*W[c][ch] ) -------
// dinv is computed on the fly as rsqrt(deg+1); deg-0 nodes get rsqrt(1)=1 automatically.

template <bool A_BF16>
__global__ __launch_bounds__(256) void gemm_mfma(const void* __restrict__ Ain,
                                                 const unsigned short* __restrict__ Wt,
                                                 const int* __restrict__ degs,
                                                 unsigned short* __restrict__ g) {
    __shared__ unsigned short lds[128 * WT_PAD];  // 34816 B; reused by epilogue
    int tid = threadIdx.x;
    int wave = tid >> 6, lane = tid & 63;
    int quad = lane >> 4, ln = lane & 15;

    {   // stage Wt (16384 shorts)
        int r = tid >> 1, h = tid & 1;
        const int4* src = (const int4*)(Wt + r * 128 + h * 64);
#pragma unroll
        for (int i = 0; i < 8; ++i)
            *(int4*)&lds[r * WT_PAD + h * 64 + i * 8] = src[i];
    }

    int row_base = blockIdx.x * 64 + wave * 16;
    int arow = row_base + ln;
    bool ok = arow < N_NODES;
    short8 afrag[4];
    if (A_BF16) {
        const unsigned short* A = (const unsigned short*)Ain;
#pragma unroll
        for (int kk = 0; kk < 4; ++kk) {
            short8 v = {};
            if (ok) v = *(const short8*)(A + arow * 128 + kk * 32 + quad * 8);
            afrag[kk] = v;
        }
    } else {
        const float* A = (const float*)Ain;
#pragma unroll
        for (int kk = 0; kk < 4; ++kk) {
            short8 v = {};
            if (ok) {
                const floatx4* p = (const floatx4*)(A + arow * 128 + kk * 32 + quad * 8);
                floatx4 fa = p[0], fb = p[1];
                v[0] = f2bf(fa.x); v[1] = f2bf(fa.y); v[2] = f2bf(fa.z); v[3] = f2bf(fa.w);
                v[4] = f2bf(fb.x); v[5] = f2bf(fb.y); v[6] = f2bf(fb.z); v[7] = f2bf(fb.w);
            }
            afrag[kk] = v;
        }
    }
    __syncthreads();

    floatx4 acc[8] = {};
#pragma unroll
    for (int n0 = 0; n0 < 8; ++n0) {
#pragma unroll
        for (int kk = 0; kk < 4; ++kk) {
            short8 b = *(const short8*)&lds[(n0 * 16 + ln) * WT_PAD + kk * 32 + quad * 8];
            acc[n0] = __builtin_amdgcn_mfma_f32_16x16x32_bf16(afrag[kk], b, acc[n0], 0, 0, 0);
        }
    }

    __syncthreads();  // done with Wt; reuse LDS for epilogue transpose
    unsigned short* st = &lds[wave * 16 * WT_PAD];
    float dv[4];
#pragma unroll
    for (int r = 0; r < 4; ++r) {
        int node = row_base + quad * 4 + r;
        dv[r] = (node < N_NODES) ? rsqrtf((float)(degs[node] + 1)) : 0.f;
    }
#pragma unroll
    for (int n0 = 0; n0 < 8; ++n0)
#pragma unroll
        for (int r = 0; r < 4; ++r)
            st[(quad * 4 + r) * WT_PAD + n0 * 16 + ln] =
                (unsigned short)f2bf(acc[n0][r] * dv[r]);
    __syncthreads();

#pragma unroll
    for (int i = 0; i < 4; ++i) {
        int row = i * 4 + quad;
        int node = row_base + row;
        short8 v = *(const short8*)&st[row * WT_PAD + ln * 8];
        if (node < N_NODES) *(short8*)(g + node * 128 + ln * 8) = v;
    }
}

// ---------------- aggregation (bf16 gather, channel-split phases; LDS-free) ------------

template <int MODE>  // 0: bf16 out [N][128]; 1: fp32 split out (x1 | x2 by half)
__global__ __launch_bounds__(256) void aggregate_bf16(const unsigned short* __restrict__ g,
                                                      const int* __restrict__ degs,
                                                      const unsigned short* __restrict__ srcs,
                                                      const float* __restrict__ bias,
                                                      void* __restrict__ outp) {
    int h = 0, nb = blockIdx.x;
    if (nb >= AGG_HALF_BLKS) { h = 1; nb -= AGG_HALF_BLKS; }
    int n = nb * 32 + (threadIdx.x >> 3);
    if (n >= N_NODES) return;
    int c4 = threadIdx.x & 7;                   // uint4 index within the half-row
    int hoff = h * 8;
    const uint4* grow = (const uint4*)g;        // 16 uint4 per full row
    uint4 u = grow[n * 16 + hoff + c4];         // self-loop term
    float a0 = bflo(u.x), a1 = bfhi(u.x), a2 = bflo(u.y), a3 = bfhi(u.y);
    float a4 = bflo(u.z), a5 = bfhi(u.z), a6 = bflo(u.w), a7 = bfhi(u.w);
    float c0 = 0.f, c1 = 0.f, c2 = 0.f, c3 = 0.f, c5 = 0.f, c6 = 0.f, c7 = 0.f, c8 = 0.f;
    int deg = degs[n];
    int degc = deg > 64 ? 64 : deg;
    int beg = n << SLOT_LOG;
    int pend = beg + ((degc + 3) & ~3);         // pad slots hold DUMMY (zero row)
    int e = beg;
    for (; e + 8 <= pend; e += 8) {
        ushort4 sa = *(const ushort4*)&srcs[e];
        ushort4 sb = *(const ushort4*)&srcs[e + 4];
        uint4 v0 = grow[sa.x * 16 + hoff + c4];
        uint4 v1 = grow[sa.y * 16 + hoff + c4];
        uint4 v2 = grow[sa.z * 16 + hoff + c4];
        uint4 v3 = grow[sa.w * 16 + hoff + c4];
        uint4 v4 = grow[sb.x * 16 + hoff + c4];
        uint4 v5 = grow[sb.y * 16 + hoff + c4];
        uint4 v6 = grow[sb.z * 16 + hoff + c4];
        uint4 v7 = grow[sb.w * 16 + hoff + c4];
        a0 += bflo(v0.x); a1 += bfhi(v0.x); a2 += bflo(v0.y); a3 += bfhi(v0.y);
        a4 += bflo(v0.z); a5 += bfhi(v0.z); a6 += bflo(v0.w); a7 += bfhi(v0.w);
        c0 += bflo(v1.x); c1 += bfhi(v1.x); c2 += bflo(v1.y); c3 += bfhi(v1.y);
        c5 += bflo(v1.z); c6 += bfhi(v1.z); c7 += bflo(v1.w); c8 += bfhi(v1.w);
        a0 += bflo(v2.x); a1 += bfhi(v2.x); a2 += bflo(v2.y); a3 += bfhi(v2.y);
        a4 += bflo(v2.z); a5 += bfhi(v2.z); a6 += bflo(v2.w); a7 += bfhi(v2.w);
        c0 += bflo(v3.x); c1 += bfhi(v3.x); c2 += bflo(v3.y); c3 += bfhi(v3.y);
        c5 += bflo(v3.z); c6 += bfhi(v3.z); c7 += bflo(v3.w); c8 += bfhi(v3.w);
        a0 += bflo(v4.x); a1 += bfhi(v4.x); a2 += bflo(v4.y); a3 += bfhi(v4.y);
        a4 += bflo(v4.z); a5 += bfhi(v4.z); a6 += bflo(v4.w); a7 += bfhi(v4.w);
        c0 += bflo(v5.x); c1 += bfhi(v5.x); c2 += bflo(v5.y); c3 += bfhi(v5.y);
        c5 += bflo(v5.z); c6 += bfhi(v5.z); c7 += bflo(v5.w); c8 += bfhi(v5.w);
        a0 += bflo(v6.x); a1 += bfhi(v6.x); a2 += bflo(v6.y); a3 += bfhi(v6.y);
        a4 += bflo(v6.z); a5 += bfhi(v6.z); a6 += bflo(v6.w); a7 += bfhi(v6.w);
        c0 += bflo(v7.x); c1 += bfhi(v7.x); c2 += bflo(v7.y); c3 += bfhi(v7.y);
        c5 += bflo(v7.z); c6 += bfhi(v7.z); c7 += bflo(v7.w); c8 += bfhi(v7.w);
    }
    if (e < pend) {  // exactly one 4-wide chunk (pend-beg is a multiple of 4)
        ushort4 sa = *(const ushort4*)&srcs[e];
        uint4 v0 = grow[sa.x * 16 + hoff + c4];
        uint4 v1 = grow[sa.y * 16 + hoff + c4];
        uint4 v2 = grow[sa.z * 16 + hoff + c4];
        uint4 v3 = grow[sa.w * 16 + hoff + c4];
        a0 += bflo(v0.x); a1 += bfhi(v0.x); a2 += bflo(v0.y); a3 += bfhi(v0.y);
        a4 += bflo(v0.z); a5 += bfhi(v0.z); a6 += bflo(v0.w); a7 += bfhi(v0.w);
        c0 += bflo(v1.x); c1 += bfhi(v1.x); c2 += bflo(v1.y); c3 += bfhi(v1.y);
        c5 += bflo(v1.z); c6 += bfhi(v1.z); c7 += bflo(v1.w); c8 += bfhi(v1.w);
        a0 += bflo(v2.x); a1 += bfhi(v2.x); a2 += bflo(v2.y); a3 += bfhi(v2.y);
        a4 += bflo(v2.z); a5 += bfhi(v2.z); a6 += bflo(v2.w); a7 += bfhi(v2.w);
        c0 += bflo(v3.x); c1 += bfhi(v3.x); c2 += bflo(v3.y); c3 += bfhi(v3.y);
        c5 += bflo(v3.z); c6 += bfhi(v3.z); c7 += bflo(v3.w); c8 += bfhi(v3.w);
    }
    a0 += c0; a1 += c1; a2 += c2; a3 += c3; a4 += c5; a5 += c6; a6 += c7; a7 += c8;
    float d = rsqrtf((float)(deg + 1));
    float4 bv0 = ((const float4*)bias)[h * 16 + c4 * 2];
    float4 bv1 = ((const float4*)bias)[h * 16 + c4 * 2 + 1];
    float o0 = fmaxf(d * a0 + bv0.x, 0.f);
    float o1 = fmaxf(d * a1 + bv0.y, 0.f);
    float o2 = fmaxf(d * a2 + bv0.z, 0.f);
    float o3 = fmaxf(d * a3 + bv0.w, 0.f);
    float o4 = fmaxf(d * a4 + bv1.x, 0.f);
    float o5 = fmaxf(d * a5 + bv1.y, 0.f);
    float o6 = fmaxf(d * a6 + bv1.z, 0.f);
    float o7 = fmaxf(d * a7 + bv1.w, 0.f);
    if (MODE == 0) {
        uint4 w;
        w.x = ((unsigned)(unsigned short)f2bf(o0)) | (((unsigned)(unsigned short)f2bf(o1)) << 16);
        w.y = ((unsigned)(unsigned short)f2bf(o2)) | (((unsigned)(unsigned short)f2bf(o3)) << 16);
        w.z = ((unsigned)(unsigned short)f2bf(o4)) | (((unsigned)(unsigned short)f2bf(o5)) << 16);
        w.w = ((unsigned)(unsigned short)f2bf(o6)) | (((unsigned)(unsigned short)f2bf(o7)) << 16);
        ((uint4*)outp)[n * 16 + hoff + c4] = w;   // hidden is reused by gemm2: keep cached
    } else {
        // half 0 == x1 exactly; half 1 == x2 exactly (64 ch each, fp32)
        // nontemporal: final output stream must not evict the 12.8 MB gather working set
        float* out = (float*)outp + (size_t)h * N_NODES * 64;
        floatx4* o = (floatx4*)out + n * 16 + c4 * 2;
        floatx4 w0; w0.x = o0; w0.y = o1; w0.z = o2; w0.w = o3;
        floatx4 w1; w1.x = o4; w1.y = o5; w1.z = o6; w1.w = o7;
        __builtin_nontemporal_store(w0, o);
        __builtin_nontemporal_store(w1, o + 1);
    }
}

// ---------------- launch ----------------

extern "C" void kernel_launch(void* const* d_in, const int* in_sizes, int n_in,
                              void* d_out, int out_size, void* d_ws, size_t ws_size,
                              hipStream_t stream) {
    const float* x  = (const float*)d_in[0];
    const int*   ei = (const int*)d_in[1];   // [2, E] int32
    const float* W1 = (const float*)d_in[2];
    const float* b1 = (const float*)d_in[3];
    const float* W2 = (const float*)d_in[4];
    const float* b2 = (const float*)d_in[5];
    const float* W3 = (const float*)d_in[6];
    const float* b3 = (const float*)d_in[7];
    float* out = (float*)d_out;

    // Workspace layout (non-overlapping; total 37,083,392 B, previously proven)
    char* w = (char*)d_ws;
    int*            counts      = (int*)(w + 0);                   // 200,000 B (true degree)
    int*            bucket_cnt  = (int*)(w + 200704);              // 3,128 B (NBUCK ints)
    unsigned short* Wt1         = (unsigned short*)(w + 204800);   // 32,768 B
    unsigned short* Wt23        = (unsigned short*)(w + 237568);   // 32,768 B
    float*          b23         = (float*)(w + 270336);            // 512 B
    unsigned*       bucket_data = (unsigned*)(w + 278528);         // 4,804,608 B (782*1536*4)
    unsigned short* sorted_src  = (unsigned short*)(w + 5083136);  // 6,400,000 B
    unsigned short* g1          = (unsigned short*)(w + 11483136); // 12,800,256 B (+dummy row)
    unsigned short* hidden      = (unsigned short*)(w + 24283392); // 12,800,000 B

    // prep (weights + bucket_cnt zero + zero dummy g row), then 2-phase CSR build
    prep_kernel<<<66, 256, 0, stream>>>(W1, W2, W3, b2, b3, Wt1, Wt23, b23, bucket_cnt,
                                        (unsigned int*)(g1 + N_NODES * 128));
    partition<<<PART_BLOCKS, 256, 0, stream>>>(ei, bucket_cnt, bucket_data);
    csr_build<<<NBUCK, 256, 0, stream>>>(bucket_data, bucket_cnt, counts, sorted_src);

    const int gemm_blocks = (N_NODES + 63) / 64;  // 782
    const int agg_blocks = 2 * AGG_HALF_BLKS;     // 3126 (two channel-half phases)

    // layer 1: g1 = bf16(dinv * (x @ W1)); hidden = bf16(relu(dinv*(self+sum)+b1))
    gemm_mfma<false><<<gemm_blocks, 256, 0, stream>>>(x, Wt1, counts, g1);
    aggregate_bf16<0><<<agg_blocks, 256, 0, stream>>>(g1, counts, sorted_src, b1, hidden);

    // layers 2+3 fused: g1 = bf16(dinv * (hidden @ [W2|W3])); out = relu split
    gemm_mfma<true><<<gemm_blocks, 256, 0, stream>>>(hidden, Wt23, counts, g1);
    aggregate_bf16<1><<<agg_blocks, 256, 0, stream>>>(g1, counts, sorted_src, b23, out);
}

// Round 8
// 190.381 us; speedup vs baseline: 2.9961x; 1.0055x over previous
//
#include <hip/hip_runtime.h>

#define N_NODES 50000
#define N_EDGES 800000
#define WT_PAD 136      // LDS row stride in shorts (272 B: 16B-aligned, 2-way-free banks)
#define DUMMY N_NODES   // g row 50000 is zeroed; CSR padding points here
#define SLOT_LOG 6      // 64 slots per node (max degree ~45 for Poisson(16))
#define AGG_BLKS 3125   // 50000/16 nodes per block (16 lanes/node, single phase)

#define NB2 782         // buckets of 64 nodes (== gemm 64-row tiles)
#define CAP 28          // edges per (block,bucket) cell; mean 5.24, P(ovfl)~7e-8/run
#define EPB 4096        // edges per partition block
#define PART_BLOCKS 196 // ceil(800000/4096)

typedef __attribute__((ext_vector_type(8))) short short8;   // 8 bf16 = one MFMA A/B frag
typedef __attribute__((ext_vector_type(4))) float floatx4;  // MFMA C/D frag / NT stores

__device__ __forceinline__ short f2bf(float f) {  // RNE float->bf16
    union { float f; unsigned u; } v; v.f = f;
    unsigned r = v.u + 0x7fff + ((v.u >> 16) & 1);
    return (short)(r >> 16);
}
__device__ __forceinline__ float bflo(unsigned u) {
    union { unsigned u; float f; } v; v.u = u << 16; return v.f;
}
__device__ __forceinline__ float bfhi(unsigned u) {
    union { unsigned u; float f; } v; v.u = u & 0xffff0000u; return v.f;
}

// -------- dispatch 1: prep (blocks 0..65) + fixed-cap 2D partition (all 196) ----------
// bd2[blk][bucket][CAP]: each block owns its cells -> no global atomics, no pre-zeroing.
// cnt2d fully written by every block. Per-block writes land in a private 85 KB region.

__global__ __launch_bounds__(256) void partition_prep(const int* __restrict__ ei,
                                                      const float* __restrict__ W1,
                                                      const float* __restrict__ W2,
                                                      const float* __restrict__ W3,
                                                      const float* __restrict__ b2,
                                                      const float* __restrict__ b3,
                                                      unsigned short* __restrict__ Wt1,
                                                      unsigned short* __restrict__ Wt23,
                                                      float* __restrict__ b23,
                                                      int* __restrict__ cnt2d,
                                                      unsigned* __restrict__ bd2,
                                                      unsigned int* __restrict__ gdummy) {
    int tid = threadIdx.x, blk = blockIdx.x;
    if (blk < 66) {                                  // prep slice (outputs used 2+ dispatches later)
        int i = blk * 256 + tid;
        if (i < 128 * 128) {
            int n = i >> 7, k = i & 127;
            Wt1[i] = (unsigned short)f2bf(W1[k * 128 + n]);
            float w = (n < 64) ? W2[k * 64 + n] : W3[k * 64 + (n - 64)];
            Wt23[i] = (unsigned short)f2bf(w);
        } else if (i < 128 * 128 + 128) {
            int k2 = i - 128 * 128;
            b23[k2] = (k2 < 64) ? b2[k2] : b3[k2 - 64];
        } else if (i < 128 * 128 + 192) {
            gdummy[i - (128 * 128 + 128)] = 0;       // 64 uints = 128 bf16 zeros
        }
    }
    __shared__ int cur[NB2];
    for (int i = tid; i < NB2; i += 256) cur[i] = 0;
    __syncthreads();
    int e0 = blk * EPB;
    int tot = N_EDGES - e0; if (tot > EPB) tot = EPB;
    for (int j = tid; j < tot; j += 256) {
        int e = e0 + j;
        int src = ei[e];
        int d = ei[N_EDGES + e];
        int b = d >> 6;
        int pos = atomicAdd(&cur[b], 1);             // LDS cursor
        if (pos < CAP)
            bd2[((size_t)blk * NB2 + b) * CAP + pos] = ((unsigned)d << 16) | (unsigned)src;
    }
    __syncthreads();
    for (int b = tid; b < NB2; b += 256) {
        int c = cur[b]; if (c > CAP) c = CAP;
        cnt2d[blk * NB2 + b] = c;
    }
}

// -------- dispatch 2: fused CSR build (64-node bucket) + MFMA gemm (same 64 rows) ------
// ctr[] stays in LDS across both phases: gemm's dinv needs no global counts round-trip.

template <bool A_BF16>
__global__ __launch_bounds__(256) void csr_gemm(const unsigned* __restrict__ bd2,
                                                const int* __restrict__ cnt2d,
                                                const void* __restrict__ Ain,
                                                const unsigned short* __restrict__ Wt,
                                                int* __restrict__ counts,
                                                unsigned short* __restrict__ sorted_src,
                                                unsigned short* __restrict__ g) {
    __shared__ unsigned short lds[128 * WT_PAD];     // 34816 B; csr slots use first 8 KB
    __shared__ int ctr[64];                          // survives into gemm phase
    int tid = threadIdx.x, b = blockIdx.x;
    uint4* slots4 = (uint4*)lds;                     // 64 rows x 64 shorts = 512 uint4
    unsigned short* slots = lds;

    if (tid < 64) ctr[tid] = 0;
    const unsigned dpat = ((unsigned)DUMMY) | (((unsigned)DUMMY) << 16);
    for (int i = tid; i < 512; i += 256) slots4[i] = make_uint4(dpat, dpat, dpat, dpat);
    __syncthreads();

    if (tid < PART_BLOCKS) {                         // thread t drains partition-block t's cell
        int cell = tid * NB2 + b;
        int c = cnt2d[cell];
        const unsigned* cp = bd2 + (size_t)cell * CAP;
        for (int j = 0; j < c; ++j) {
            unsigned w = cp[j];
            int dl = (int)((w >> 16) & 63);
            int r = atomicAdd(&ctr[dl], 1);          // LDS atomic
            if (r < 64) slots[(dl << 6) + r] = (unsigned short)(w & 0xffffu);
        }
    }
    __syncthreads();

    int node0 = b << 6;
    if (tid < 64 && node0 + tid < N_NODES) counts[node0 + tid] = ctr[tid];
    uint4* gs = (uint4*)(sorted_src + ((size_t)node0 << SLOT_LOG));
    for (int k = tid; k < 512; k += 256) {           // coalesced slot flush
        int row = k >> 3;
        if (node0 + row < N_NODES) gs[k] = slots4[k];
    }
    __syncthreads();                                 // slots flushed; lds reused for Wt

    // ---- gemm phase: g[n] = bf16( rsqrt(ctr[n]+1) * (A @ W)[n] ) ----
    int wave = tid >> 6, lane = tid & 63;
    int quad = lane >> 4, ln = lane & 15;
    {   // stage Wt (16384 shorts)
        int r = tid >> 1, h = tid & 1;
        const int4* src = (const int4*)(Wt + r * 128 + h * 64);
#pragma unroll
        for (int i = 0; i < 8; ++i)
            *(int4*)&lds[r * WT_PAD + h * 64 + i * 8] = src[i];
    }
    int row_base = node0 + wave * 16;
    int arow = row_base + ln;
    bool ok = arow < N_NODES;
    short8 afrag[4];
    if (A_BF16) {
        const unsigned short* A = (const unsigned short*)Ain;
#pragma unroll
        for (int kk = 0; kk < 4; ++kk) {
            short8 v = {};
            if (ok) v = *(const short8*)(A + arow * 128 + kk * 32 + quad * 8);
            afrag[kk] = v;
        }
    } else {
        const float* A = (const float*)Ain;
#pragma unroll
        for (int kk = 0; kk < 4; ++kk) {
            short8 v = {};
            if (ok) {
                const floatx4* p = (const floatx4*)(A + arow * 128 + kk * 32 + quad * 8);
                floatx4 fa = p[0], fb = p[1];
                v[0] = f2bf(fa.x); v[1] = f2bf(fa.y); v[2] = f2bf(fa.z); v[3] = f2bf(fa.w);
                v[4] = f2bf(fb.x); v[5] = f2bf(fb.y); v[6] = f2bf(fb.z); v[7] = f2bf(fb.w);
            }
            afrag[kk] = v;
        }
    }
    __syncthreads();

    floatx4 acc[8] = {};
#pragma unroll
    for (int n0 = 0; n0 < 8; ++n0) {
#pragma unroll
        for (int kk = 0; kk < 4; ++kk) {
            short8 bb = *(const short8*)&lds[(n0 * 16 + ln) * WT_PAD + kk * 32 + quad * 8];
            acc[n0] = __builtin_amdgcn_mfma_f32_16x16x32_bf16(afrag[kk], bb, acc[n0], 0, 0, 0);
        }
    }

    __syncthreads();  // done with Wt; reuse LDS for epilogue transpose
    unsigned short* st = &lds[wave * 16 * WT_PAD];
    float dv[4];
#pragma unroll
    for (int r = 0; r < 4; ++r) {
        int node = row_base + quad * 4 + r;
        dv[r] = (node < N_NODES) ? rsqrtf((float)(ctr[wave * 16 + quad * 4 + r] + 1)) : 0.f;
    }
#pragma unroll
    for (int n0 = 0; n0 < 8; ++n0)
#pragma unroll
        for (int r = 0; r < 4; ++r)
            st[(quad * 4 + r) * WT_PAD + n0 * 16 + ln] =
                (unsigned short)f2bf(acc[n0][r] * dv[r]);
    __syncthreads();

#pragma unroll
    for (int i = 0; i < 4; ++i) {
        int row = i * 4 + quad;
        int node = row_base + row;
        short8 v = *(const short8*)&st[row * WT_PAD + ln * 8];
        if (node < N_NODES) *(short8*)(g + node * 128 + ln * 8) = v;
    }
}

// -------- dispatch 4: standalone MFMA gemm (layer 2+3), dinv from global counts --------

__global__ __launch_bounds__(256) void gemm_mfma(const unsigned short* __restrict__ A,
                                                 const unsigned short* __restrict__ Wt,
                                                 const int* __restrict__ degs,
                                                 unsigned short* __restrict__ g) {
    __shared__ unsigned short lds[128 * WT_PAD];  // 34816 B; reused by epilogue
    int tid = threadIdx.x;
    int wave = tid >> 6, lane = tid & 63;
    int quad = lane >> 4, ln = lane & 15;

    {   // stage Wt (16384 shorts)
        int r = tid >> 1, h = tid & 1;
        const int4* src = (const int4*)(Wt + r * 128 + h * 64);
#pragma unroll
        for (int i = 0; i < 8; ++i)
            *(int4*)&lds[r * WT_PAD + h * 64 + i * 8] = src[i];
    }

    int row_base = blockIdx.x * 64 + wave * 16;
    int arow = row_base + ln;
    bool ok = arow < N_NODES;
    short8 afrag[4];
#pragma unroll
    for (int kk = 0; kk < 4; ++kk) {
        short8 v = {};
        if (ok) v = *(const short8*)(A + arow * 128 + kk * 32 + quad * 8);
        afrag[kk] = v;
    }
    __syncthreads();

    floatx4 acc[8] = {};
#pragma unroll
    for (int n0 = 0; n0 < 8; ++n0) {
#pragma unroll
        for (int kk = 0; kk < 4; ++kk) {
            short8 b = *(const short8*)&lds[(n0 * 16 + ln) * WT_PAD + kk * 32 + quad * 8];
            acc[n0] = __builtin_amdgcn_mfma_f32_16x16x32_bf16(afrag[kk], b, acc[n0], 0, 0, 0);
        }
    }

    __syncthreads();  // done with Wt; reuse LDS for epilogue transpose
    unsigned short* st = &lds[wave * 16 * WT_PAD];
    float dv[4];
#pragma unroll
    for (int r = 0; r < 4; ++r) {
        int node = row_base + quad * 4 + r;
        dv[r] = (node < N_NODES) ? rsqrtf((float)(degs[node] + 1)) : 0.f;
    }
#pragma unroll
    for (int n0 = 0; n0 < 8; ++n0)
#pragma unroll
        for (int r = 0; r < 4; ++r)
            st[(quad * 4 + r) * WT_PAD + n0 * 16 + ln] =
                (unsigned short)f2bf(acc[n0][r] * dv[r]);
    __syncthreads();

#pragma unroll
    for (int i = 0; i < 4; ++i) {
        int row = i * 4 + quad;
        int node = row_base + row;
        short8 v = *(const short8*)&st[row * WT_PAD + ln * 8];
        if (node < N_NODES) *(short8*)(g + node * 128 + ln * 8) = v;
    }
}

// -------- dispatches 3/5: aggregation, 16 lanes/node, single phase ---------------------
// Same 800k lanes / 8 accumulators / 16B-per-edge-per-lane as the proven round-3 shape,
// but srcs/degs read once (not twice) and per-node loop overhead paid once.

template <int MODE>  // 0: bf16 out [N][128]; 1: fp32 split out (x1 | x2 by channel half)
__global__ __launch_bounds__(256) void aggregate_bf16(const unsigned short* __restrict__ g,
                                                      const int* __restrict__ degs,
                                                      const unsigned short* __restrict__ srcs,
                                                      const float* __restrict__ bias,
                                                      void* __restrict__ outp) {
    int n = blockIdx.x * 16 + (threadIdx.x >> 4);    // 3125*16 = 50000 exactly
    int c4 = threadIdx.x & 15;                       // uint4 index within the 256 B row
    const uint4* grow = (const uint4*)g;             // 16 uint4 per row
    uint4 u = grow[n * 16 + c4];                     // self-loop term
    float a0 = bflo(u.x), a1 = bfhi(u.x), a2 = bflo(u.y), a3 = bfhi(u.y);
    float a4 = bflo(u.z), a5 = bfhi(u.z), a6 = bflo(u.w), a7 = bfhi(u.w);
    float c0 = 0.f, c1 = 0.f, c2 = 0.f, c3 = 0.f, c5 = 0.f, c6 = 0.f, c7 = 0.f, c8 = 0.f;
    int deg = degs[n];
    int degc = deg > 64 ? 64 : deg;
    int beg = n << SLOT_LOG;
    int pend = beg + ((degc + 3) & ~3);              // pad slots hold DUMMY (zero row)
    int e = beg;
    for (; e + 8 <= pend; e += 8) {
        ushort4 sa = *(const ushort4*)&srcs[e];
        ushort4 sb = *(const ushort4*)&srcs[e + 4];
        uint4 v0 = grow[sa.x * 16 + c4];
        uint4 v1 = grow[sa.y * 16 + c4];
        uint4 v2 = grow[sa.z * 16 + c4];
        uint4 v3 = grow[sa.w * 16 + c4];
        uint4 v4 = grow[sb.x * 16 + c4];
        uint4 v5 = grow[sb.y * 16 + c4];
        uint4 v6 = grow[sb.z * 16 + c4];
        uint4 v7 = grow[sb.w * 16 + c4];
        a0 += bflo(v0.x); a1 += bfhi(v0.x); a2 += bflo(v0.y); a3 += bfhi(v0.y);
        a4 += bflo(v0.z); a5 += bfhi(v0.z); a6 += bflo(v0.w); a7 += bfhi(v0.w);
        c0 += bflo(v1.x); c1 += bfhi(v1.x); c2 += bflo(v1.y); c3 += bfhi(v1.y);
        c5 += bflo(v1.z); c6 += bfhi(v1.z); c7 += bflo(v1.w); c8 += bfhi(v1.w);
        a0 += bflo(v2.x); a1 += bfhi(v2.x); a2 += bflo(v2.y); a3 += bfhi(v2.y);
        a4 += bflo(v2.z); a5 += bfhi(v2.z); a6 += bflo(v2.w); a7 += bfhi(v2.w);
        c0 += bflo(v3.x); c1 += bfhi(v3.x); c2 += bflo(v3.y); c3 += bfhi(v3.y);
        c5 += bflo(v3.z); c6 += bfhi(v3.z); c7 += bflo(v3.w); c8 += bfhi(v3.w);
        a0 += bflo(v4.x); a1 += bfhi(v4.x); a2 += bflo(v4.y); a3 += bfhi(v4.y);
        a4 += bflo(v4.z); a5 += bfhi(v4.z); a6 += bflo(v4.w); a7 += bfhi(v4.w);
        c0 += bflo(v5.x); c1 += bfhi(v5.x); c2 += bflo(v5.y); c3 += bfhi(v5.y);
        c5 += bflo(v5.z); c6 += bfhi(v5.z); c7 += bflo(v5.w); c8 += bfhi(v5.w);
        a0 += bflo(v6.x); a1 += bfhi(v6.x); a2 += bflo(v6.y); a3 += bfhi(v6.y);
        a4 += bflo(v6.z); a5 += bfhi(v6.z); a6 += bflo(v6.w); a7 += bfhi(v6.w);
        c0 += bflo(v7.x); c1 += bfhi(v7.x); c2 += bflo(v7.y); c3 += bfhi(v7.y);
        c5 += bflo(v7.z); c6 += bfhi(v7.z); c7 += bflo(v7.w); c8 += bfhi(v7.w);
    }
    if (e < pend) {  // exactly one 4-wide chunk (pend-beg is a multiple of 4)
        ushort4 sa = *(const ushort4*)&srcs[e];
        uint4 v0 = grow[sa.x * 16 + c4];
        uint4 v1 = grow[sa.y * 16 + c4];
        uint4 v2 = grow[sa.z * 16 + c4];
        uint4 v3 = grow[sa.w * 16 + c4];
        a0 += bflo(v0.x); a1 += bfhi(v0.x); a2 += bflo(v0.y); a3 += bfhi(v0.y);
        a4 += bflo(v0.z); a5 += bfhi(v0.z); a6 += bflo(v0.w); a7 += bfhi(v0.w);
        c0 += bflo(v1.x); c1 += bfhi(v1.x); c2 += bflo(v1.y); c3 += bfhi(v1.y);
        c5 += bflo(v1.z); c6 += bfhi(v1.z); c7 += bflo(v1.w); c8 += bfhi(v1.w);
        a0 += bflo(v2.x); a1 += bfhi(v2.x); a2 += bflo(v2.y); a3 += bfhi(v2.y);
        a4 += bflo(v2.z); a5 += bfhi(v2.z); a6 += bflo(v2.w); a7 += bfhi(v2.w);
        c0 += bflo(v3.x); c1 += bfhi(v3.x); c2 += bflo(v3.y); c3 += bfhi(v3.y);
        c5 += bflo(v3.z); c6 += bfhi(v3.z); c7 += bflo(v3.w); c8 += bfhi(v3.w);
    }
    a0 += c0; a1 += c1; a2 += c2; a3 += c3; a4 += c5; a5 += c6; a6 += c7; a7 += c8;
    float d = rsqrtf((float)(deg + 1));
    float4 bv0 = ((const float4*)bias)[c4 * 2];      // channels c4*8 .. c4*8+7
    float4 bv1 = ((const float4*)bias)[c4 * 2 + 1];
    float o0 = fmaxf(d * a0 + bv0.x, 0.f);
    float o1 = fmaxf(d * a1 + bv0.y, 0.f);
    float o2 = fmaxf(d * a2 + bv0.z, 0.f);
    float o3 = fmaxf(d * a3 + bv0.w, 0.f);
    float o4 = fmaxf(d * a4 + bv1.x, 0.f);
    float o5 = fmaxf(d * a5 + bv1.y, 0.f);
    float o6 = fmaxf(d * a6 + bv1.z, 0.f);
    float o7 = fmaxf(d * a7 + bv1.w, 0.f);
    if (MODE == 0) {
        uint4 w;
        w.x = ((unsigned)(unsigned short)f2bf(o0)) | (((unsigned)(unsigned short)f2bf(o1)) << 16);
        w.y = ((unsigned)(unsigned short)f2bf(o2)) | (((unsigned)(unsigned short)f2bf(o3)) << 16);
        w.z = ((unsigned)(unsigned short)f2bf(o4)) | (((unsigned)(unsigned short)f2bf(o5)) << 16);
        w.w = ((unsigned)(unsigned short)f2bf(o6)) | (((unsigned)(unsigned short)f2bf(o7)) << 16);
        ((uint4*)outp)[n * 16 + c4] = w;             // hidden is reused by gemm2: keep cached
    } else {
        // half 0 == x1 exactly; half 1 == x2 exactly (64 ch each, fp32)
        // nontemporal: final output stream must not evict the 12.8 MB gather working set
        int hh = c4 >> 3, cc = c4 & 7;
        float* out = (float*)outp + (size_t)hh * N_NODES * 64;
        floatx4* o = (floatx4*)out + n * 16 + cc * 2;
        floatx4 w0; w0.x = o0; w0.y = o1; w0.z = o2; w0.w = o3;
        floatx4 w1; w1.x = o4; w1.y = o5; w1.z = o6; w1.w = o7;
        __builtin_nontemporal_store(w0, o);
        __builtin_nontemporal_store(w1, o + 1);
    }
}

// ---------------- launch (5 dispatches) ----------------

extern "C" void kernel_launch(void* const* d_in, const int* in_sizes, int n_in,
                              void* d_out, int out_size, void* d_ws, size_t ws_size,
                              hipStream_t stream) {
    const float* x  = (const float*)d_in[0];
    const int*   ei = (const int*)d_in[1];   // [2, E] int32
    const float* W1 = (const float*)d_in[2];
    const float* b1 = (const float*)d_in[3];
    const float* W2 = (const float*)d_in[4];
    const float* b2 = (const float*)d_in[5];
    const float* W3 = (const float*)d_in[6];
    const float* b3 = (const float*)d_in[7];
    float* out = (float*)d_out;

    // Workspace layout. bd2 (17.17 MB, dead after csr_gemm1) overlays hidden (written
    // first by agg1). Total 37,248,128 B < 38,490,112 previously proven.
    char* w = (char*)d_ws;
    int*            counts     = (int*)(w + 0);                   // 200,000 B (true degree)
    int*            cnt2d      = (int*)(w + 200704);              // 613,088 B (196*782 ints)
    unsigned short* Wt1        = (unsigned short*)(w + 815104);   // 32,768 B
    unsigned short* Wt23       = (unsigned short*)(w + 847872);   // 32,768 B
    float*          b23        = (float*)(w + 880640);            // 512 B
    unsigned short* sorted_src = (unsigned short*)(w + 881152);   // 6,400,000 B
    unsigned short* g1         = (unsigned short*)(w + 7281152);  // 12,800,256 B (+dummy row)
    unsigned*       bd2        = (unsigned*)(w + 20081664);       // 17,166,464 B (196*782*28*4)
    unsigned short* hidden     = (unsigned short*)(w + 20081664); // 12,800,000 B (overlays bd2)

    partition_prep<<<PART_BLOCKS, 256, 0, stream>>>(ei, W1, W2, W3, b2, b3, Wt1, Wt23, b23,
                                                    cnt2d, bd2,
                                                    (unsigned int*)(g1 + N_NODES * 128));

    // layer 1 (fused CSR + gemm): g1 = bf16(dinv * (x @ W1)); then hidden via aggregate
    csr_gemm<false><<<NB2, 256, 0, stream>>>(bd2, cnt2d, x, Wt1, counts, sorted_src, g1);
    aggregate_bf16<0><<<AGG_BLKS, 256, 0, stream>>>(g1, counts, sorted_src, b1, hidden);

    // layers 2+3 fused: g1 = bf16(dinv * (hidden @ [W2|W3])); out = relu split
    gemm_mfma<<<NB2, 256, 0, stream>>>(hidden, Wt23, counts, g1);
    aggregate_bf16<1><<<AGG_BLKS, 256, 0, stream>>>(g1, counts, sorted_src, b23, out);
}